// Round 15
// baseline (386.570 us; speedup 1.0000x reference)
//
#include <hip/hip_runtime.h>
#include <math.h>

#define N_NODES 50000
#define N_EDGES 800000
#define B_ 512
#define S_ 200
#define D_ 128
#define BS_ (B_*S_)            // 102400 rows, full batch
#define KSTR 26                // Kl row stride (u16): 13 dwords, odd -> conflict-free
#define VSTR 234               // Vt row stride (u16): 117 dwords, odd -> conflict-free

typedef unsigned short u16;
typedef unsigned int u32;
using bfrag = __attribute__((ext_vector_type(8))) short;
using f32x4 = __attribute__((ext_vector_type(4))) float;
using i32x4 = __attribute__((ext_vector_type(4))) int;

__device__ __forceinline__ float exp2fast(float x) { return __builtin_amdgcn_exp2f(x); }

__device__ __forceinline__ u16 f2bf(float f) {        // round-half-up f32->bf16 (2 ops)
  return (u16)((__float_as_uint(f) + 0x8000u) >> 16);
}
__device__ __forceinline__ float bf2f(u16 v) { return __uint_as_float(((u32)v) << 16); }
__device__ __forceinline__ float bflo(u32 v) { return __uint_as_float(v << 16); }
__device__ __forceinline__ float bfhi(u32 v) { return __uint_as_float(v & 0xffff0000u); }
__device__ __forceinline__ u32 pack2(float a, float b) {
  return (u32)f2bf(a) | ((u32)f2bf(b) << 16);
}
#define MFMA16(a, b, c) __builtin_amdgcn_mfma_f32_16x16x32_bf16((a), (b), (c), 0, 0, 0)

// stage a 128x128 bf16 weight (row-major [c][k]) into padded LDS sW[128][136]
#define STAGE_W(Wsrc) \
  for (int i_ = threadIdx.x; i_ < 2048; i_ += 256) { \
    int c_ = i_ >> 4, kg_ = i_ & 15; \
    *(uint4*)(sW + c_ * 136 + kg_ * 8) = *(const uint4*)((Wsrc) + c_ * 128 + kg_ * 8); \
  }

// -------------------- fused prep: zero cnt + 8 transposes + 3 products + pc + f2bf8
__global__ __launch_bounds__(256) void prep_kernel(
    int* __restrict__ cnt,
    const float* __restrict__ gcn_w0, const float* __restrict__ gcn_w1,
    const float* __restrict__ gcn_w2, const float* __restrict__ lin0_w,
    const float* __restrict__ lin3_w, const float* __restrict__ mha_wo,
    const float* __restrict__ ffn0_w, const float* __restrict__ ffn1_w,
    const float* __restrict__ lin1_w, const float* __restrict__ lin2_w,
    const float* __restrict__ mha_wq, const float* __restrict__ mha_wk,
    const float* __restrict__ mha_wv, const float* __restrict__ corr_emb,
    const float* __restrict__ lin0_b, const float* __restrict__ pos_emb,
    const float* __restrict__ node_x,
    u16* __restrict__ g0T, u16* __restrict__ g1T, u16* __restrict__ g2T,
    u16* __restrict__ l0T, u16* __restrict__ l3T, u16* __restrict__ woT,
    u16* __restrict__ f0T, u16* __restrict__ f1T,
    u16* __restrict__ wqT, u16* __restrict__ wkT, u16* __restrict__ wvT,
    float* __restrict__ pc, u16* __restrict__ xb) {
  int bb = blockIdx.x;
  int t = threadIdx.x;
  if (bb < 196) {                         // zero cnt
    int i = bb * 256 + t;
    if (i < N_NODES) cnt[i] = 0;
  } else if (bb < 708) {                  // plain transpose W[k][c] -> D[c][k]
    int idx = bb - 196;
    const float* W; u16* D;
    switch (idx >> 6) {
      case 0: W = gcn_w0; D = g0T; break;
      case 1: W = gcn_w1; D = g1T; break;
      case 2: W = gcn_w2; D = g2T; break;
      case 3: W = lin0_w; D = l0T; break;
      case 4: W = lin3_w; D = l3T; break;
      case 5: W = mha_wo; D = woT; break;
      case 6: W = ffn0_w; D = f0T; break;
      default: W = ffn1_w; D = f1T; break;
    }
    int i = (idx & 63) * 256 + t;
    int k = i >> 7, c = i & 127;
    D[c * 128 + k] = f2bf(W[k * 128 + c]);
  } else if (bb < 900) {                  // (X@Y)^T -> D
    int idx = bb - 708;
    const float* X; const float* Y; u16* D;
    switch (idx >> 6) {
      case 0: X = lin3_w; Y = mha_wq; D = wqT; break;
      case 1: X = lin2_w; Y = mha_wk; D = wkT; break;
      default: X = lin1_w; Y = mha_wv; D = wvT; break;
    }
    int i = (idx & 63) * 256 + t;
    int k = i >> 7, c = i & 127;
    float acc = 0.f;
    for (int q = 0; q < 128; ++q) acc += X[k * 128 + q] * Y[q * 128 + c];
    D[c * 128 + k] = f2bf(acc);
  } else if (bb < 1100) {                 // pc[a][s][c] = lin0_b + pos_emb + corr@lin0_w[128:]
    int i = (bb - 900) * 256 + t;         // 51200
    int c = i & 127, s = (i >> 7) % S_, a = i / (128 * S_);
    float acc = lin0_b[c] + pos_emb[s * 128 + c];
    for (int q = 0; q < 128; ++q)
      acc += corr_emb[a * 128 + q] * lin0_w[(128 + q) * 128 + c];
    pc[i] = acc;
  } else {                                // f2bf8: node_x -> xb
    int i = (bb - 1100) * 256 + t;        // 800000
    if (i < N_NODES * 16) {
      float4 a4 = ((const float4*)node_x)[i * 2];
      float4 b4 = ((const float4*)node_x)[i * 2 + 1];
      uint4 o;
      o.x = pack2(a4.x, a4.y); o.y = pack2(a4.z, a4.w);
      o.z = pack2(b4.x, b4.y); o.w = pack2(b4.z, b4.w);
      ((uint4*)xb)[i] = o;
    }
  }
}

// ---------------------------------------------------------------- graph prep
__global__ void hist_kernel(const int* __restrict__ dst, int* __restrict__ cnt, int E) {
  int e = blockIdx.x * 256 + threadIdx.x;
  if (e < E) atomicAdd(&cnt[dst[e]], 1);
}

__global__ __launch_bounds__(1024) void scanA_kernel(
    const int* __restrict__ cnt, int* __restrict__ locpref,
    int* __restrict__ btot, float* __restrict__ dis, int N) {
  __shared__ int wsum[16];
  int t = threadIdx.x, lane = t & 63, wid = t >> 6;
  int i = blockIdx.x * 1024 + t;
  int v = (i < N) ? cnt[i] : 0;
  if (i < N) dis[i] = rsqrtf(1.f + (float)v);
  int x = v;
  #pragma unroll
  for (int off = 1; off < 64; off <<= 1) {
    int y = __shfl_up(x, off);
    if (lane >= off) x += y;
  }
  if (lane == 63) wsum[wid] = x;
  __syncthreads();
  if (wid == 0 && lane < 16) {
    int s = wsum[lane];
    #pragma unroll
    for (int off = 1; off < 16; off <<= 1) {
      int y = __shfl_up(s, off);
      if (lane >= off) s += y;
    }
    wsum[lane] = s;
  }
  __syncthreads();
  int woff = (wid > 0) ? wsum[wid - 1] : 0;
  if (i < N) locpref[i] = woff + x - v;
  if (t == 1023) btot[blockIdx.x] = woff + x;
}

__global__ void scanB_kernel(const int* __restrict__ btot, int* __restrict__ boff, int nb) {
  int lane = threadIdx.x;
  int v = (lane < nb) ? btot[lane] : 0;
  int x = v;
  #pragma unroll
  for (int off = 1; off < 64; off <<= 1) {
    int y = __shfl_up(x, off);
    if (lane >= off) x += y;
  }
  if (lane < nb) boff[lane] = x - v;
}

__global__ void scanC_kernel(const int* __restrict__ locpref, const int* __restrict__ boff,
                             int* __restrict__ row_ptr, int* __restrict__ fill, int N) {
  int i = blockIdx.x * 256 + threadIdx.x;
  if (i < N) {
    int r = locpref[i] + boff[i >> 10];
    row_ptr[i] = r; fill[i] = r;
  }
  if (i == 0) row_ptr[N] = N_EDGES;
}

__global__ void scatter_kernel(const int* __restrict__ src, const int* __restrict__ dst,
                               int* __restrict__ fill, int* __restrict__ csr_src, int E) {
  int e = blockIdx.x * 256 + threadIdx.x;
  if (e >= E) return;
  int d = dst[e];
  int pos = atomicAdd(&fill[d], 1);
  csr_src[pos] = src[e];
}

// ------------------------------------------------------------ MFMA bf16 GEMM
// (GCN layers) block-staged weight; LDS-bounce coalesced uint4 stores.
__global__ __launch_bounds__(256) void gemm_bf16_kernel(
    const u16* __restrict__ A, const u16* __restrict__ wT,
    u16* __restrict__ C, int M) {
  __shared__ u16 sW[128 * 136];
  __shared__ u16 ldsb[4][16 * 136];
  int t = threadIdx.x;
  int w = t >> 6, l = t & 63, lr = l & 15, lg = l >> 4;
  int r0 = blockIdx.x * 64 + w * 16;

  int row = r0 + lr;
  const u16* Arow = A + (size_t)(row < M ? row : 0) * 128;

  bfrag a[4];
  #pragma unroll
  for (int ks = 0; ks < 4; ++ks) a[ks] = *(const bfrag*)(Arow + ks * 32 + lg * 8);

  STAGE_W(wT);
  __syncthreads();

  f32x4 acc[8];
  #pragma unroll
  for (int ct = 0; ct < 8; ++ct) acc[ct] = (f32x4){0.f, 0.f, 0.f, 0.f};
  #pragma unroll
  for (int ks = 0; ks < 4; ++ks)
    #pragma unroll
    for (int ct = 0; ct < 8; ++ct) {
      bfrag b = *(const bfrag*)(sW + (ct * 16 + lr) * 136 + ks * 32 + lg * 8);
      acc[ct] = MFMA16(a[ks], b, acc[ct]);
    }
  #pragma unroll
  for (int ct = 0; ct < 8; ++ct)
    #pragma unroll
    for (int i = 0; i < 4; ++i)
      ldsb[w][(lg * 4 + i) * 136 + ct * 16 + lr] = f2bf(acc[ct][i]);
  #pragma unroll
  for (int j = 0; j < 4; ++j) {
    int c = j * 64 + l;
    int rw = c >> 4, ch = c & 15;
    int r = r0 + rw;
    if (r < M)
      *(uint4*)(C + (size_t)r * 128 + ch * 8) = *(const uint4*)&ldsb[w][rw * 136 + ch * 8];
  }
}

// ------------------------------------------------------------- GCN aggregate
// wave per node; 16 colgrp x 4 edgegrp, 4 edges per edgegrp in flight (16 total)
__global__ __launch_bounds__(256) void agg_kernel(
    const u16* __restrict__ xw, const float* __restrict__ dis,
    const int* __restrict__ row_ptr, const int* __restrict__ csr_src,
    const float* __restrict__ bias, const float* __restrict__ lng,
    const float* __restrict__ lnb, u16* __restrict__ out, int N, int doLN) {
  int t = threadIdx.x;
  int n = blockIdx.x * 4 + (t >> 6);
  if (n >= N) return;
  int l = t & 63, cg = l & 15, eg = l >> 4;
  float dn = dis[n];
  float acc[8] = {0.f, 0.f, 0.f, 0.f, 0.f, 0.f, 0.f, 0.f};
  if (eg == 0) {
    uint4 r = *(const uint4*)(xw + (size_t)n * 128 + cg * 8);
    float w = dn * dn;
    acc[0] += w * bflo(r.x); acc[1] += w * bfhi(r.x);
    acc[2] += w * bflo(r.y); acc[3] += w * bfhi(r.y);
    acc[4] += w * bflo(r.z); acc[5] += w * bfhi(r.z);
    acc[6] += w * bflo(r.w); acc[7] += w * bfhi(r.w);
  }
  int e1 = row_ptr[n + 1];
  int e = row_ptr[n] + eg;
  int sn0 = (e < e1) ? csr_src[e] : -1;
  int sn1 = (e + 4 < e1) ? csr_src[e + 4] : -1;
  int sn2 = (e + 8 < e1) ? csr_src[e + 8] : -1;
  int sn3 = (e + 12 < e1) ? csr_src[e + 12] : -1;
  while (sn0 >= 0) {
    int s0 = sn0;
    int s1 = (sn1 >= 0) ? sn1 : s0;
    int s2 = (sn2 >= 0) ? sn2 : s0;
    int s3 = (sn3 >= 0) ? sn3 : s0;
    float w0 = dis[s0] * dn;
    float w1 = (sn1 >= 0) ? dis[s1] * dn : 0.f;
    float w2 = (sn2 >= 0) ? dis[s2] * dn : 0.f;
    float w3 = (sn3 >= 0) ? dis[s3] * dn : 0.f;
    e += 16;
    sn0 = (e < e1) ? csr_src[e] : -1;
    sn1 = (e + 4 < e1) ? csr_src[e + 4] : -1;
    sn2 = (e + 8 < e1) ? csr_src[e + 8] : -1;
    sn3 = (e + 12 < e1) ? csr_src[e + 12] : -1;
    uint4 r0 = *(const uint4*)(xw + (size_t)s0 * 128 + cg * 8);
    uint4 r1 = *(const uint4*)(xw + (size_t)s1 * 128 + cg * 8);
    uint4 r2 = *(const uint4*)(xw + (size_t)s2 * 128 + cg * 8);
    uint4 r3 = *(const uint4*)(xw + (size_t)s3 * 128 + cg * 8);
    acc[0] += w0 * bflo(r0.x); acc[1] += w0 * bfhi(r0.x);
    acc[2] += w0 * bflo(r0.y); acc[3] += w0 * bfhi(r0.y);
    acc[4] += w0 * bflo(r0.z); acc[5] += w0 * bfhi(r0.z);
    acc[6] += w0 * bflo(r0.w); acc[7] += w0 * bfhi(r0.w);
    acc[0] += w1 * bflo(r1.x); acc[1] += w1 * bfhi(r1.x);
    acc[2] += w1 * bflo(r1.y); acc[3] += w1 * bfhi(r1.y);
    acc[4] += w1 * bflo(r1.z); acc[5] += w1 * bfhi(r1.z);
    acc[6] += w1 * bflo(r1.w); acc[7] += w1 * bfhi(r1.w);
    acc[0] += w2 * bflo(r2.x); acc[1] += w2 * bfhi(r2.x);
    acc[2] += w2 * bflo(r2.y); acc[3] += w2 * bfhi(r2.y);
    acc[4] += w2 * bflo(r2.z); acc[5] += w2 * bfhi(r2.z);
    acc[6] += w2 * bflo(r2.w); acc[7] += w2 * bfhi(r2.w);
    acc[0] += w3 * bflo(r3.x); acc[1] += w3 * bfhi(r3.x);
    acc[2] += w3 * bflo(r3.y); acc[3] += w3 * bfhi(r3.y);
    acc[4] += w3 * bflo(r3.z); acc[5] += w3 * bfhi(r3.z);
    acc[6] += w3 * bflo(r3.w); acc[7] += w3 * bfhi(r3.w);
  }
  #pragma unroll
  for (int j = 0; j < 8; ++j) {
    acc[j] += __shfl_xor(acc[j], 16);
    acc[j] += __shfl_xor(acc[j], 32);
  }
  int c0 = cg * 8;
  #pragma unroll
  for (int j = 0; j < 8; ++j) acc[j] = fmaxf(acc[j] + bias[c0 + j], 0.f);
  if (doLN) {
    float s1 = 0.f, s2 = 0.f;
    #pragma unroll
    for (int j = 0; j < 8; ++j) { s1 += acc[j]; s2 += acc[j] * acc[j]; }
    #pragma unroll
    for (int off = 1; off < 16; off <<= 1) {
      s1 += __shfl_xor(s1, off);
      s2 += __shfl_xor(s2, off);
    }
    float mean = s1 * (1.f / 128.f);
    float var = s2 * (1.f / 128.f) - mean * mean;
    float inv = rsqrtf(var + 1e-5f);
    #pragma unroll
    for (int j = 0; j < 8; ++j)
      acc[j] = (acc[j] - mean) * inv * lng[c0 + j] + lnb[c0 + j];
  }
  if (eg == 0) {
    uint4 o;
    o.x = pack2(acc[0], acc[1]); o.y = pack2(acc[2], acc[3]);
    o.z = pack2(acc[4], acc[5]); o.w = pack2(acc[6], acc[7]);
    *(uint4*)(out + (size_t)n * 128 + cg * 8) = o;
  }
}

// ----------------------- merged QKV with block-level weight staging in LDS
// role A (inter->kh,vh) / role B (qh, pre-scaled by 0.25*log2(e) for exp2).
__global__ __launch_bounds__(256) void qkv_kernel(
    const u16* __restrict__ xa, const int* __restrict__ hist,
    const int* __restrict__ ans, const int* __restrict__ nseq,
    const u16* __restrict__ l0T, const float* __restrict__ pc,
    const u16* __restrict__ wkT, const float* __restrict__ bk,
    const u16* __restrict__ wvT, const float* __restrict__ bv,
    const u16* __restrict__ wqT, const float* __restrict__ bq,
    u16* __restrict__ khout, u16* __restrict__ vhout,
    u16* __restrict__ qhout, int nblk) {
  __shared__ u16 sW[128 * 136];        // staged weight, padded stride
  __shared__ u16 ldsb[4][16 * 136];    // per-wave bounce
  int bb = blockIdx.x;
  int t = threadIdx.x, w = t >> 6, l = t & 63, lr = l & 15, lg = l >> 4;
  f32x4 acc[8];

  if (bb < nblk) {
    // ---- role A ----
    int r0 = bb * 64 + w * 16;
    int arow = hist[r0 + lr];
    const u16* Arow = xa + (size_t)arow * 128;
    bfrag a[4];
    #pragma unroll
    for (int ks = 0; ks < 4; ++ks) a[ks] = *(const bfrag*)(Arow + ks * 32 + lg * 8);

    STAGE_W(l0T);
    __syncthreads();
    #pragma unroll
    for (int ct = 0; ct < 8; ++ct) acc[ct] = (f32x4){0.f, 0.f, 0.f, 0.f};
    #pragma unroll
    for (int ks = 0; ks < 4; ++ks)
      #pragma unroll
      for (int ct = 0; ct < 8; ++ct) {
        bfrag b = *(const bfrag*)(sW + (ct * 16 + lr) * 136 + ks * 32 + lg * 8);
        acc[ct] = MFMA16(a[ks], b, acc[ct]);
      }
    int pcoff[4];
    #pragma unroll
    for (int i = 0; i < 4; ++i) {
      int r = r0 + lg * 4 + i;
      pcoff[i] = (ans[r] * S_ + (r % S_)) * 128;
    }
    #pragma unroll
    for (int ct = 0; ct < 8; ++ct) {
      int col = ct * 16 + lr;
      #pragma unroll
      for (int i = 0; i < 4; ++i)
        ldsb[w][(lg * 4 + i) * 136 + col] = f2bf(acc[ct][i] + pc[pcoff[i] + col]);
    }
    bfrag a2[4];
    #pragma unroll
    for (int ks = 0; ks < 4; ++ks)
      a2[ks] = *(const bfrag*)(&ldsb[w][lr * 136 + ks * 32 + lg * 8]);
    __syncthreads();           // all waves done reading sW(l0T)

    STAGE_W(wkT);
    __syncthreads();
    #pragma unroll
    for (int ct = 0; ct < 8; ++ct) acc[ct] = (f32x4){0.f, 0.f, 0.f, 0.f};
    #pragma unroll
    for (int ks = 0; ks < 4; ++ks)
      #pragma unroll
      for (int ct = 0; ct < 8; ++ct) {
        bfrag b = *(const bfrag*)(sW + (ct * 16 + lr) * 136 + ks * 32 + lg * 8);
        acc[ct] = MFMA16(a2[ks], b, acc[ct]);
      }
    #pragma unroll
    for (int ct = 0; ct < 8; ++ct)
      #pragma unroll
      for (int i = 0; i < 4; ++i)
        ldsb[w][(lg * 4 + i) * 136 + ct * 16 + lr] = f2bf(acc[ct][i] + bk[ct * 16 + lr]);
    #pragma unroll
    for (int j = 0; j < 4; ++j) {
      int c = j * 64 + l;
      int head = c >> 5, rw = (c >> 1) & 15, half = c & 1;
      *(uint4*)(khout + ((size_t)head * BS_ + r0 + rw) * 16 + half * 8) =
          *(const uint4*)&ldsb[w][rw * 136 + head * 16 + half * 8];
    }
    __syncthreads();           // done reading sW(wkT)

    STAGE_W(wvT);
    __syncthreads();
    #pragma unroll
    for (int ct = 0; ct < 8; ++ct) acc[ct] = (f32x4){0.f, 0.f, 0.f, 0.f};
    #pragma unroll
    for (int ks = 0; ks < 4; ++ks)
      #pragma unroll
      for (int ct = 0; ct < 8; ++ct) {
        bfrag b = *(const bfrag*)(sW + (ct * 16 + lr) * 136 + ks * 32 + lg * 8);
        acc[ct] = MFMA16(a2[ks], b, acc[ct]);
      }
    #pragma unroll
    for (int ct = 0; ct < 8; ++ct)
      #pragma unroll
      for (int i = 0; i < 4; ++i)
        ldsb[w][(lg * 4 + i) * 136 + ct * 16 + lr] = f2bf(acc[ct][i] + bv[ct * 16 + lr]);
    #pragma unroll
    for (int j = 0; j < 4; ++j) {
      int c = j * 64 + l;
      int head = c >> 5, rw = (c >> 1) & 15, half = c & 1;
      *(uint4*)(vhout + ((size_t)head * BS_ + r0 + rw) * 16 + half * 8) =
          *(const uint4*)&ldsb[w][rw * 136 + head * 16 + half * 8];
    }
  } else {
    // ---- role B: qh scaled by 0.25*log2(e) (exp2 form of score scale) ----
    int r0 = (bb - nblk) * 64 + w * 16;
    int arow = nseq[r0 + lr];
    const u16* Arow = xa + (size_t)arow * 128;
    bfrag a[4];
    #pragma unroll
    for (int ks = 0; ks < 4; ++ks) a[ks] = *(const bfrag*)(Arow + ks * 32 + lg * 8);

    STAGE_W(wqT);
    __syncthreads();
    #pragma unroll
    for (int ct = 0; ct < 8; ++ct) acc[ct] = (f32x4){0.f, 0.f, 0.f, 0.f};
    #pragma unroll
    for (int ks = 0; ks < 4; ++ks)
      #pragma unroll
      for (int ct = 0; ct < 8; ++ct) {
        bfrag b = *(const bfrag*)(sW + (ct * 16 + lr) * 136 + ks * 32 + lg * 8);
        acc[ct] = MFMA16(a[ks], b, acc[ct]);
      }
    #pragma unroll
    for (int ct = 0; ct < 8; ++ct)
      #pragma unroll
      for (int i = 0; i < 4; ++i)
        ldsb[w][(lg * 4 + i) * 136 + ct * 16 + lr] =
            f2bf((acc[ct][i] + bq[ct * 16 + lr]) * 0.36067376022224085f);
    #pragma unroll
    for (int j = 0; j < 4; ++j) {
      int c = j * 64 + l;
      int head = c >> 5, rw = (c >> 1) & 15, half = c & 1;
      *(uint4*)(qhout + ((size_t)head * BS_ + r0 + rw) * 16 + half * 8) =
          *(const uint4*)&ldsb[w][rw * 136 + head * 16 + half * 8];
    }
  }
}

// ----------------------------------------------------------- MFMA attention
// Register-P flash attention via swapped operands; exp2; conflict-free pads.
__global__ __launch_bounds__(256) void attn_mfma_kernel(
    u16* qh_ao, const u16* __restrict__ kh, const u16* __restrict__ vh) {
  __shared__ u16 Kl[208 * KSTR];   // [key][d0..15] pad 26
  __shared__ u16 Vt[16 * VSTR];    // [d][key], keys>=200 zero, pad 234
  int b = blockIdx.x >> 3, h = blockIdx.x & 7;
  int t = threadIdx.x;
  size_t base = ((size_t)h * BS_ + (size_t)b * S_) * 16;

  for (int i = t; i < 208 * 2; i += 256) {
    int key = i >> 1, d = (i & 1) * 8;
    uint4 v = make_uint4(0, 0, 0, 0);
    if (key < S_) v = *(const uint4*)(kh + base + (size_t)key * 16 + d);
    *(uint4*)(Kl + key * KSTR + d) = v;
  }
  for (int i = t; i < 16 * VSTR; i += 256) {
    int d = i / VSTR, key = i - d * VSTR;
    Vt[d * VSTR + key] = (key < S_) ? vh[base + (size_t)key * 16 + d] : (u16)0;
  }
  __syncthreads();

  int w = t >> 6, l = t & 63, lr = l & 15, lg = l >> 4;
  const f32x4 zero4 = {0.f, 0.f, 0.f, 0.f};
  const bfrag zerob = (bfrag){0, 0, 0, 0, 0, 0, 0, 0};
  u32 qpack = (w == 0) ? 0xFC71u : (w == 1) ? 0xFB80u : (w == 2) ? 0xFA92u : 0x6543u;
  int srcA = lr + ((lg & 1) << 5);
  int srcB = srcA + 16;
  bool hiTile = (lg >= 2);

  for (int s = 0; s < 4; ++s) {
    int qi = (qpack >> (4 * s)) & 15;
    if (qi == 15) break;
    int qrow = qi * 16 + lr;
    bfrag qf = zerob;
    if (lg < 2 && qrow < S_)
      qf = *(const bfrag*)(qh_ao + base + (size_t)qrow * 16 + lg * 8);
    float rsum = 0.f;
    f32x4 o = zero4;
    int ktmax = (qi + 2) >> 1;
    for (int kt = 0; kt < ktmax; ++kt) {
      int kj0 = kt * 2, kj1 = kt * 2 + 1;
      u32 P0t0, P1t0, P0t1 = 0, P1t1 = 0;
      {
        bfrag kf = zerob;
        if (lg < 2) kf = *(const bfrag*)(Kl + (kj0 * 16 + lr) * KSTR + lg * 8);
        f32x4 sc = MFMA16(kf, qf, zero4);
        float p0, p1, p2, p3;
        if (kj0 == qi) {
          p0 = (lg * 4 + 0 <= lr) ? exp2fast(sc[0]) : 0.f;
          p1 = (lg * 4 + 1 <= lr) ? exp2fast(sc[1]) : 0.f;
          p2 = (lg * 4 + 2 <= lr) ? exp2fast(sc[2]) : 0.f;
          p3 = (lg * 4 + 3 <= lr) ? exp2fast(sc[3]) : 0.f;
        } else {
          p0 = exp2fast(sc[0]); p1 = exp2fast(sc[1]);
          p2 = exp2fast(sc[2]); p3 = exp2fast(sc[3]);
        }
        rsum += (p0 + p1) + (p2 + p3);
        P0t0 = pack2(p0, p1); P1t0 = pack2(p2, p3);
      }
      if (kj1 <= qi) {
        bfrag kf = zerob;
        if (lg < 2) kf = *(const bfrag*)(Kl + (kj1 * 16 + lr) * KSTR + lg * 8);
        f32x4 sc = MFMA16(kf, qf, zero4);
        float p0, p1, p2, p3;
        if (kj1 == qi) {
          p0 = (lg * 4 + 0 <= lr) ? exp2fast(sc[0]) : 0.f;
          p1 = (lg * 4 + 1 <= lr) ? exp2fast(sc[1]) : 0.f;
          p2 = (lg * 4 + 2 <= lr) ? exp2fast(sc[2]) : 0.f;
          p3 = (lg * 4 + 3 <= lr) ? exp2fast(sc[3]) : 0.f;
        } else {
          p0 = exp2fast(sc[0]); p1 = exp2fast(sc[1]);
          p2 = exp2fast(sc[2]); p3 = exp2fast(sc[3]);
        }
        rsum += (p0 + p1) + (p2 + p3);
        P0t1 = pack2(p0, p1); P1t1 = pack2(p2, p3);
      }
      u32 x0 = __shfl(P0t0, srcA), x1 = __shfl(P1t0, srcA);
      u32 x2 = __shfl(P0t0, srcB), x3 = __shfl(P1t0, srcB);
      u32 y0 = __shfl(P0t1, srcA), y1 = __shfl(P1t1, srcA);
      u32 y2 = __shfl(P0t1, srcB), y3 = __shfl(P1t1, srcB);
      i32x4 pi;
      pi[0] = (int)(hiTile ? y0 : x0);
      pi[1] = (int)(hiTile ? y1 : x1);
      pi[2] = (int)(hiTile ? y2 : x2);
      pi[3] = (int)(hiTile ? y3 : x3);
      bfrag pb = __builtin_bit_cast(bfrag, pi);
      bfrag vf = *(const bfrag*)(Vt + lr * VSTR + kt * 32 + lg * 8);
      o = MFMA16(vf, pb, o);
    }
    rsum += __shfl_xor(rsum, 16);
    rsum += __shfl_xor(rsum, 32);
    if (qrow < S_) {
      float inv = 1.f / rsum;
      uint2 ov;
      ov.x = pack2(o[0] * inv, o[1] * inv);
      ov.y = pack2(o[2] * inv, o[3] * inv);
      *(uint2*)(qh_ao + base + (size_t)qrow * 16 + lg * 4) = ov;
    }
  }
}

// ---- fused output with staged weights:
// ao@wo + gather(new)@l3T + bo -> LN2 -> FFN -> LN3 -> pred
__global__ __launch_bounds__(256) void out_kernel(
    const u16* __restrict__ ao, const u16* __restrict__ xa,
    const int* __restrict__ nseq,
    const u16* __restrict__ woT, const float* __restrict__ bo,
    const u16* __restrict__ l3T,
    const float* __restrict__ g2, const float* __restrict__ b2,
    const u16* __restrict__ f0T, const float* __restrict__ b0f,
    const u16* __restrict__ f1T, const float* __restrict__ b1f,
    const float* __restrict__ g3, const float* __restrict__ b3,
    const float* __restrict__ w4, const float* __restrict__ b4,
    float* __restrict__ pred) {
  __shared__ u16 sW[128 * 136];
  __shared__ u16 ldsb[4][16 * 136];
  int t = threadIdx.x, w = t >> 6, l = t & 63, lr = l & 15, lg = l >> 4;
  int r0 = blockIdx.x * 64 + w * 16;

  bfrag a_ao[4], a_xa[4];
  #pragma unroll
  for (int ks = 0; ks < 4; ++ks) {
    int head = ks * 2 + (lg >> 1);
    int d0 = (lg & 1) * 8;
    a_ao[ks] = *(const bfrag*)(ao + ((size_t)head * BS_ + r0 + lr) * 16 + d0);
  }
  {
    int arow = nseq[r0 + lr];
    const u16* Arow = xa + (size_t)arow * 128;
    #pragma unroll
    for (int ks = 0; ks < 4; ++ks) a_xa[ks] = *(const bfrag*)(Arow + ks * 32 + lg * 8);
  }

  f32x4 acc[8];
  #pragma unroll
  for (int ct = 0; ct < 8; ++ct) acc[ct] = (f32x4){0.f, 0.f, 0.f, 0.f};

  STAGE_W(woT);
  __syncthreads();
  #pragma unroll
  for (int ks = 0; ks < 4; ++ks)
    #pragma unroll
    for (int ct = 0; ct < 8; ++ct) {
      bfrag b = *(const bfrag*)(sW + (ct * 16 + lr) * 136 + ks * 32 + lg * 8);
      acc[ct] = MFMA16(a_ao[ks], b, acc[ct]);
    }
  __syncthreads();

  STAGE_W(l3T);
  __syncthreads();
  #pragma unroll
  for (int ks = 0; ks < 4; ++ks)
    #pragma unroll
    for (int ct = 0; ct < 8; ++ct) {
      bfrag b = *(const bfrag*)(sW + (ct * 16 + lr) * 136 + ks * 32 + lg * 8);
      acc[ct] = MFMA16(a_xa[ks], b, acc[ct]);
    }
  __syncthreads();

  #pragma unroll
  for (int ct = 0; ct < 8; ++ct) {
    float bcol = bo[ct * 16 + lr];
    #pragma unroll
    for (int i = 0; i < 4; ++i) acc[ct][i] += bcol;
  }
  // LN2 -> acc holds atn (f32); bounce to ldsb; read a2 frags
  bfrag a2[4];
  {
    float s1[4] = {0, 0, 0, 0}, s2[4] = {0, 0, 0, 0};
    #pragma unroll
    for (int ct = 0; ct < 8; ++ct)
      #pragma unroll
      for (int i = 0; i < 4; ++i) {
        s1[i] += acc[ct][i];
        s2[i] += acc[ct][i] * acc[ct][i];
      }
    #pragma unroll
    for (int i = 0; i < 4; ++i) {
      s1[i] += __shfl_xor(s1[i], 1); s2[i] += __shfl_xor(s2[i], 1);
      s1[i] += __shfl_xor(s1[i], 2); s2[i] += __shfl_xor(s2[i], 2);
      s1[i] += __shfl_xor(s1[i], 4); s2[i] += __shfl_xor(s2[i], 4);
      s1[i] += __shfl_xor(s1[i], 8); s2[i] += __shfl_xor(s2[i], 8);
    }
    float mean[4], inv[4];
    #pragma unroll
    for (int i = 0; i < 4; ++i) {
      mean[i] = s1[i] * (1.f / 128.f);
      float var = s2[i] * (1.f / 128.f) - mean[i] * mean[i];
      inv[i] = rsqrtf(var + 1e-5f);
    }
    #pragma unroll
    for (int ct = 0; ct < 8; ++ct) {
      int col = ct * 16 + lr;
      float gc = g2[col], bc = b2[col];
      #pragma unroll
      for (int i = 0; i < 4; ++i) {
        acc[ct][i] = (acc[ct][i] - mean[i]) * inv[i] * gc + bc;
        ldsb[w][(lg * 4 + i) * 136 + col] = f2bf(acc[ct][i]);
      }
    }
    #pragma unroll
    for (int ks = 0; ks < 4; ++ks)
      a2[ks] = *(const bfrag*)(&ldsb[w][lr * 136 + ks * 32 + lg * 8]);
  }

  STAGE_W(f0T);
  __syncthreads();
  f32x4 acc2[8];
  #pragma unroll
  for (int ct = 0; ct < 8; ++ct) acc2[ct] = (f32x4){0.f, 0.f, 0.f, 0.f};
  #pragma unroll
  for (int ks = 0; ks < 4; ++ks)
    #pragma unroll
    for (int ct = 0; ct < 8; ++ct) {
      bfrag b = *(const bfrag*)(sW + (ct * 16 + lr) * 136 + ks * 32 + lg * 8);
      acc2[ct] = MFMA16(a2[ks], b, acc2[ct]);
    }
  #pragma unroll
  for (int ct = 0; ct < 8; ++ct) {
    int col = ct * 16 + lr;
    float bcol = b0f[col];
    #pragma unroll
    for (int i = 0; i < 4; ++i)
      ldsb[w][(lg * 4 + i) * 136 + col] = f2bf(fmaxf(acc2[ct][i] + bcol, 0.f));
  }
  #pragma unroll
  for (int ks = 0; ks < 4; ++ks)
    a2[ks] = *(const bfrag*)(&ldsb[w][lr * 136 + ks * 32 + lg * 8]);
  __syncthreads();

  STAGE_W(f1T);
  __syncthreads();
  #pragma unroll
  for (int ct = 0; ct < 8; ++ct) acc2[ct] = (f32x4){0.f, 0.f, 0.f, 0.f};
  #pragma unroll
  for (int ks = 0; ks < 4; ++ks)
    #pragma unroll
    for (int ct = 0; ct < 8; ++ct) {
      bfrag b = *(const bfrag*)(sW + (ct * 16 + lr) * 136 + ks * 32 + lg * 8);
      acc2[ct] = MFMA16(a2[ks], b, acc2[ct]);
    }
  #pragma unroll
  for (int ct = 0; ct < 8; ++ct) {
    int col = ct * 16 + lr;
    float bcol = b1f[col];
    #pragma unroll
    for (int i = 0; i < 4; ++i) acc2[ct][i] += bcol + acc[ct][i];
  }
  // LN3 -> dot w4 -> pred
  {
    float s1[4] = {0, 0, 0, 0}, s2[4] = {0, 0, 0, 0};
    #pragma unroll
    for (int ct = 0; ct < 8; ++ct)
      #pragma unroll
      for (int i = 0; i < 4; ++i) {
        s1[i] += acc2[ct][i];
        s2[i] += acc2[ct][i] * acc2[ct][i];
      }
    #pragma unroll
    for (int i = 0; i < 4; ++i) {
      s1[i] += __shfl_xor(s1[i], 1); s2[i] += __shfl_xor(s2[i], 1);
      s1[i] += __shfl_xor(s1[i], 2); s2[i] += __shfl_xor(s2[i], 2);
      s1[i] += __shfl_xor(s1[i], 4); s2[i] += __shfl_xor(s2[i], 4);
      s1[i] += __shfl_xor(s1[i], 8); s2[i] += __shfl_xor(s2[i], 8);
    }
    float p[4] = {0, 0, 0, 0};
    #pragma unroll
    for (int i = 0; i < 4; ++i) {
      float mean = s1[i] * (1.f / 128.f);
      float var = s2[i] * (1.f / 128.f) - mean * mean;
      float inv = rsqrtf(var + 1e-5f);
      #pragma unroll
      for (int ct = 0; ct < 8; ++ct) {
        int col = ct * 16 + lr;
        p[i] += ((acc2[ct][i] - mean) * inv * g3[col] + b3[col]) * w4[col];
      }
    }
    #pragma unroll
    for (int i = 0; i < 4; ++i) {
      p[i] += __shfl_xor(p[i], 1);
      p[i] += __shfl_xor(p[i], 2);
      p[i] += __shfl_xor(p[i], 4);
      p[i] += __shfl_xor(p[i], 8);
    }
    if (lr == 0) {
      float bias4 = b4[0];
      #pragma unroll
      for (int i = 0; i < 4; ++i) pred[r0 + lg * 4 + i] = p[i] + bias4;
    }
  }
}

// ---------------------------------------------------------------------------
extern "C" void kernel_launch(void* const* d_in, const int* in_sizes, int n_in,
                              void* d_out, int out_size, void* d_ws, size_t ws_size,
                              hipStream_t stream) {
  const int* hist_seq = (const int*)d_in[0];
  const int* hist_ans = (const int*)d_in[1];
  const int* new_seq = (const int*)d_in[2];
  const int* edge_index = (const int*)d_in[3];
  const float* node_x = (const float*)d_in[4];
  const float* gcn_w0 = (const float*)d_in[5];
  const float* gcn_b0 = (const float*)d_in[6];
  const float* gcn_w1 = (const float*)d_in[7];
  const float* gcn_b1 = (const float*)d_in[8];
  const float* gcn_w2 = (const float*)d_in[9];
  const float* gcn_b2 = (const float*)d_in[10];
  const float* ln0_g = (const float*)d_in[11];
  const float* ln0_b = (const float*)d_in[12];
  const float* ln1_g = (const float*)d_in[13];
  const float* ln1_b = (const float*)d_in[14];
  const float* ln2_g = (const float*)d_in[15];
  const float* ln2_b = (const float*)d_in[16];
  const float* ln3_g = (const float*)d_in[17];
  const float* ln3_b = (const float*)d_in[18];
  const float* corr_emb = (const float*)d_in[19];
  const float* lin0_w = (const float*)d_in[20];
  const float* lin0_b = (const float*)d_in[21];
  const float* lin1_w = (const float*)d_in[22];
  const float* lin2_w = (const float*)d_in[23];
  const float* lin3_w = (const float*)d_in[24];
  const float* lin4_w = (const float*)d_in[25];
  const float* lin4_b = (const float*)d_in[26];
  const float* pos_emb = (const float*)d_in[27];
  const float* mha_wq = (const float*)d_in[28];
  const float* mha_bq = (const float*)d_in[29];
  const float* mha_wk = (const float*)d_in[30];
  const float* mha_bk = (const float*)d_in[31];
  const float* mha_wv = (const float*)d_in[32];
  const float* mha_bv = (const float*)d_in[33];
  const float* mha_wo = (const float*)d_in[34];
  const float* mha_bo = (const float*)d_in[35];
  const float* ffn0_w = (const float*)d_in[36];
  const float* ffn0_b = (const float*)d_in[37];
  const float* ffn1_w = (const float*)d_in[38];
  const float* ffn1_b = (const float*)d_in[39];
  (void)in_sizes; (void)n_in; (void)out_size;

  char* ws = (char*)d_ws;
  size_t off = 0;
  auto alloc = [&](size_t bytes) -> void* {
    void* p = ws + off;
    off += (bytes + 255) & ~(size_t)255;
    return p;
  };
  int* cnt = (int*)alloc((size_t)N_NODES * 4);
  int* row_ptr = (int*)alloc((size_t)(N_NODES + 1) * 4);
  int* fill = (int*)alloc((size_t)N_NODES * 4);
  int* locpref = (int*)alloc((size_t)N_NODES * 4);
  int* btot = (int*)alloc(64 * 4);
  int* boff = (int*)alloc(64 * 4);
  float* dis = (float*)alloc((size_t)N_NODES * 4);
  int* csr_src = (int*)alloc((size_t)N_EDGES * 4);
  const size_t WB = 128 * 128 * 2;
  u16* g0T = (u16*)alloc(WB);
  u16* g1T = (u16*)alloc(WB);
  u16* g2T = (u16*)alloc(WB);
  u16* l0T = (u16*)alloc(WB);
  u16* l3T = (u16*)alloc(WB);
  u16* woT = (u16*)alloc(WB);
  u16* f0T = (u16*)alloc(WB);
  u16* f1T = (u16*)alloc(WB);
  u16* wqT = (u16*)alloc(WB);
  u16* wkT = (u16*)alloc(WB);
  u16* wvT = (u16*)alloc(WB);
  float* pc = (float*)alloc((size_t)2 * S_ * 128 * 4);
  u16* xa = (u16*)alloc((size_t)N_NODES * 128 * 2);
  const size_t CB = (size_t)BS_ * 128 * 2;   // 26.2 MB
  size_t RB = off;
  u16* bufQ = (u16*)(ws + RB);                // qh -> ao in place, head-major
  u16* bufK = (u16*)(ws + RB + CB);           // kh head-major
  u16* bufV = (u16*)(ws + RB + 2 * CB);       // vh head-major
  u16* xb = bufQ;                             // overlay: dead before qkv writes
  u16* xw = bufQ + (size_t)N_NODES * 128;
  size_t need = RB + 3 * CB;
  if (ws_size < need) return;     // diagnostic guard

  // ---- fused prep (zero cnt, weight transposes/products, pc, node_x cast) ----
  prep_kernel<<<4225, 256, 0, stream>>>(cnt, gcn_w0, gcn_w1, gcn_w2, lin0_w, lin3_w,
                                        mha_wo, ffn0_w, ffn1_w, lin1_w, lin2_w,
                                        mha_wq, mha_wk, mha_wv, corr_emb, lin0_b,
                                        pos_emb, node_x, g0T, g1T, g2T, l0T, l3T,
                                        woT, f0T, f1T, wqT, wkT, wvT, pc, xb);
  // ---- graph prep ----
  int nb = (N_NODES + 1023) / 1024;   // 49
  hist_kernel<<<(N_EDGES + 255) / 256, 256, 0, stream>>>(edge_index + N_EDGES, cnt, N_EDGES);
  scanA_kernel<<<nb, 1024, 0, stream>>>(cnt, locpref, btot, dis, N_NODES);
  scanB_kernel<<<1, 64, 0, stream>>>(btot, boff, nb);
  scanC_kernel<<<(N_NODES + 255) / 256, 256, 0, stream>>>(locpref, boff, row_ptr, fill, N_NODES);
  scatter_kernel<<<(N_EDGES + 255) / 256, 256, 0, stream>>>(edge_index, edge_index + N_EDGES,
                                                            fill, csr_src, N_EDGES);

  int gN = (N_NODES + 63) / 64;
  int aN = (N_NODES + 3) / 4;

  // ---- GCN ----
  gemm_bf16_kernel<<<gN, 256, 0, stream>>>(xb, g0T, xw, N_NODES);
  agg_kernel<<<aN, 256, 0, stream>>>(xw, dis, row_ptr, csr_src, gcn_b0, ln0_g, ln0_b, xa, N_NODES, 1);
  gemm_bf16_kernel<<<gN, 256, 0, stream>>>(xa, g1T, xw, N_NODES);
  agg_kernel<<<aN, 256, 0, stream>>>(xw, dis, row_ptr, csr_src, gcn_b1, ln1_g, ln1_b, xa, N_NODES, 1);
  gemm_bf16_kernel<<<gN, 256, 0, stream>>>(xa, g2T, xw, N_NODES);
  agg_kernel<<<aN, 256, 0, stream>>>(xw, dis, row_ptr, csr_src, gcn_b2, nullptr, nullptr, xa, N_NODES, 0);

  // ---- transformer, full batch, 3 dispatches ----
  int gT = BS_ / 64;   // 1600
  qkv_kernel<<<2 * gT, 256, 0, stream>>>(xa, hist_seq, hist_ans, new_seq,
                                         l0T, pc, wkT, mha_bk, wvT, mha_bv,
                                         wqT, mha_bq, bufK, bufV, bufQ, gT);
  attn_mfma_kernel<<<B_ * 8, 256, 0, stream>>>(bufQ, bufK, bufV);
  out_kernel<<<gT, 256, 0, stream>>>(bufQ, xa, new_seq, woT, mha_bo, l3T,
                                     ln2_g, ln2_b, f0T, ffn0_b, f1T, ffn1_b,
                                     ln3_g, ln3_b, lin4_w, lin4_b, (float*)d_out);
}

// Round 16
// 381.858 us; speedup vs baseline: 1.0123x; 1.0123x over previous
//
#include <hip/hip_runtime.h>
#include <math.h>

#define N_NODES 50000
#define N_EDGES 800000
#define B_ 512
#define S_ 200
#define D_ 128
#define BS_ (B_*S_)            // 102400 rows, full batch
#define KSTR 24                // Kl row stride (u16): 2-way read alias only (free)
#define VSTR 232               // Vt row stride (u16)

typedef unsigned short u16;
typedef unsigned int u32;
using bfrag = __attribute__((ext_vector_type(8))) short;
using f32x4 = __attribute__((ext_vector_type(4))) float;
using i32x4 = __attribute__((ext_vector_type(4))) int;

__device__ __forceinline__ float exp2fast(float x) { return __builtin_amdgcn_exp2f(x); }

__device__ __forceinline__ u16 f2bf(float f) {        // round-half-up f32->bf16 (2 ops)
  return (u16)((__float_as_uint(f) + 0x8000u) >> 16);
}
__device__ __forceinline__ float bf2f(u16 v) { return __uint_as_float(((u32)v) << 16); }
__device__ __forceinline__ float bflo(u32 v) { return __uint_as_float(v << 16); }
__device__ __forceinline__ float bfhi(u32 v) { return __uint_as_float(v & 0xffff0000u); }
__device__ __forceinline__ u32 pack2(float a, float b) {
  return (u32)f2bf(a) | ((u32)f2bf(b) << 16);
}
#define MFMA16(a, b, c) __builtin_amdgcn_mfma_f32_16x16x32_bf16((a), (b), (c), 0, 0, 0)

// stage a 128x128 bf16 weight (row-major [c][k]) into padded LDS sW[128][136]
#define STAGE_W(Wsrc) \
  for (int i_ = threadIdx.x; i_ < 2048; i_ += 256) { \
    int c_ = i_ >> 4, kg_ = i_ & 15; \
    *(uint4*)(sW + c_ * 136 + kg_ * 8) = *(const uint4*)((Wsrc) + c_ * 128 + kg_ * 8); \
  }

// -------------------- fused prep: zero cnt + 8 transposes + 3 products + pc + f2bf8
__global__ __launch_bounds__(256) void prep_kernel(
    int* __restrict__ cnt,
    const float* __restrict__ gcn_w0, const float* __restrict__ gcn_w1,
    const float* __restrict__ gcn_w2, const float* __restrict__ lin0_w,
    const float* __restrict__ lin3_w, const float* __restrict__ mha_wo,
    const float* __restrict__ ffn0_w, const float* __restrict__ ffn1_w,
    const float* __restrict__ lin1_w, const float* __restrict__ lin2_w,
    const float* __restrict__ mha_wq, const float* __restrict__ mha_wk,
    const float* __restrict__ mha_wv, const float* __restrict__ corr_emb,
    const float* __restrict__ lin0_b, const float* __restrict__ pos_emb,
    const float* __restrict__ node_x,
    u16* __restrict__ g0T, u16* __restrict__ g1T, u16* __restrict__ g2T,
    u16* __restrict__ l0T, u16* __restrict__ l3T, u16* __restrict__ woT,
    u16* __restrict__ f0T, u16* __restrict__ f1T,
    u16* __restrict__ wqT, u16* __restrict__ wkT, u16* __restrict__ wvT,
    float* __restrict__ pc, u16* __restrict__ xb) {
  int bb = blockIdx.x;
  int t = threadIdx.x;
  if (bb < 196) {                         // zero cnt
    int i = bb * 256 + t;
    if (i < N_NODES) cnt[i] = 0;
  } else if (bb < 708) {                  // plain transpose W[k][c] -> D[c][k]
    int idx = bb - 196;
    const float* W; u16* D;
    switch (idx >> 6) {
      case 0: W = gcn_w0; D = g0T; break;
      case 1: W = gcn_w1; D = g1T; break;
      case 2: W = gcn_w2; D = g2T; break;
      case 3: W = lin0_w; D = l0T; break;
      case 4: W = lin3_w; D = l3T; break;
      case 5: W = mha_wo; D = woT; break;
      case 6: W = ffn0_w; D = f0T; break;
      default: W = ffn1_w; D = f1T; break;
    }
    int i = (idx & 63) * 256 + t;
    int k = i >> 7, c = i & 127;
    D[c * 128 + k] = f2bf(W[k * 128 + c]);
  } else if (bb < 900) {                  // (X@Y)^T -> D
    int idx = bb - 708;
    const float* X; const float* Y; u16* D;
    switch (idx >> 6) {
      case 0: X = lin3_w; Y = mha_wq; D = wqT; break;
      case 1: X = lin2_w; Y = mha_wk; D = wkT; break;
      default: X = lin1_w; Y = mha_wv; D = wvT; break;
    }
    int i = (idx & 63) * 256 + t;
    int k = i >> 7, c = i & 127;
    float acc = 0.f;
    for (int q = 0; q < 128; ++q) acc += X[k * 128 + q] * Y[q * 128 + c];
    D[c * 128 + k] = f2bf(acc);
  } else if (bb < 1100) {                 // pc[a][s][c] = lin0_b + pos_emb + corr@lin0_w[128:]
    int i = (bb - 900) * 256 + t;         // 51200
    int c = i & 127, s = (i >> 7) % S_, a = i / (128 * S_);
    float acc = lin0_b[c] + pos_emb[s * 128 + c];
    for (int q = 0; q < 128; ++q)
      acc += corr_emb[a * 128 + q] * lin0_w[(128 + q) * 128 + c];
    pc[i] = acc;
  } else {                                // f2bf8: node_x -> xb
    int i = (bb - 1100) * 256 + t;        // 800000
    if (i < N_NODES * 16) {
      float4 a4 = ((const float4*)node_x)[i * 2];
      float4 b4 = ((const float4*)node_x)[i * 2 + 1];
      uint4 o;
      o.x = pack2(a4.x, a4.y); o.y = pack2(a4.z, a4.w);
      o.z = pack2(b4.x, b4.y); o.w = pack2(b4.z, b4.w);
      ((uint4*)xb)[i] = o;
    }
  }
}

// ---------------------------------------------------------------- graph prep
__global__ void hist_kernel(const int* __restrict__ dst, int* __restrict__ cnt, int E) {
  int e = blockIdx.x * 256 + threadIdx.x;
  if (e < E) atomicAdd(&cnt[dst[e]], 1);
}

__global__ __launch_bounds__(1024) void scanA_kernel(
    const int* __restrict__ cnt, int* __restrict__ locpref,
    int* __restrict__ btot, float* __restrict__ dis, int N) {
  __shared__ int wsum[16];
  int t = threadIdx.x, lane = t & 63, wid = t >> 6;
  int i = blockIdx.x * 1024 + t;
  int v = (i < N) ? cnt[i] : 0;
  if (i < N) dis[i] = rsqrtf(1.f + (float)v);
  int x = v;
  #pragma unroll
  for (int off = 1; off < 64; off <<= 1) {
    int y = __shfl_up(x, off);
    if (lane >= off) x += y;
  }
  if (lane == 63) wsum[wid] = x;
  __syncthreads();
  if (wid == 0 && lane < 16) {
    int s = wsum[lane];
    #pragma unroll
    for (int off = 1; off < 16; off <<= 1) {
      int y = __shfl_up(s, off);
      if (lane >= off) s += y;
    }
    wsum[lane] = s;
  }
  __syncthreads();
  int woff = (wid > 0) ? wsum[wid - 1] : 0;
  if (i < N) locpref[i] = woff + x - v;
  if (t == 1023) btot[blockIdx.x] = woff + x;
}

__global__ void scanB_kernel(const int* __restrict__ btot, int* __restrict__ boff, int nb) {
  int lane = threadIdx.x;
  int v = (lane < nb) ? btot[lane] : 0;
  int x = v;
  #pragma unroll
  for (int off = 1; off < 64; off <<= 1) {
    int y = __shfl_up(x, off);
    if (lane >= off) x += y;
  }
  if (lane < nb) boff[lane] = x - v;
}

__global__ void scanC_kernel(const int* __restrict__ locpref, const int* __restrict__ boff,
                             int* __restrict__ row_ptr, int* __restrict__ fill, int N) {
  int i = blockIdx.x * 256 + threadIdx.x;
  if (i < N) {
    int r = locpref[i] + boff[i >> 10];
    row_ptr[i] = r; fill[i] = r;
  }
  if (i == 0) row_ptr[N] = N_EDGES;
}

__global__ void scatter_kernel(const int* __restrict__ src, const int* __restrict__ dst,
                               int* __restrict__ fill, int* __restrict__ csr_src, int E) {
  int e = blockIdx.x * 256 + threadIdx.x;
  if (e >= E) return;
  int d = dst[e];
  int pos = atomicAdd(&fill[d], 1);
  csr_src[pos] = src[e];
}

// ------------------------------------------------------------ MFMA bf16 GEMM
// (GCN layers) block-staged weight; LDS-bounce coalesced uint4 stores.
__global__ __launch_bounds__(256) void gemm_bf16_kernel(
    const u16* __restrict__ A, const u16* __restrict__ wT,
    u16* __restrict__ C, int M) {
  __shared__ u16 sW[128 * 136];
  __shared__ u16 ldsb[4][16 * 136];
  int t = threadIdx.x;
  int w = t >> 6, l = t & 63, lr = l & 15, lg = l >> 4;
  int r0 = blockIdx.x * 64 + w * 16;

  int row = r0 + lr;
  const u16* Arow = A + (size_t)(row < M ? row : 0) * 128;

  bfrag a[4];
  #pragma unroll
  for (int ks = 0; ks < 4; ++ks) a[ks] = *(const bfrag*)(Arow + ks * 32 + lg * 8);

  STAGE_W(wT);
  __syncthreads();

  f32x4 acc[8];
  #pragma unroll
  for (int ct = 0; ct < 8; ++ct) acc[ct] = (f32x4){0.f, 0.f, 0.f, 0.f};
  #pragma unroll
  for (int ks = 0; ks < 4; ++ks)
    #pragma unroll
    for (int ct = 0; ct < 8; ++ct) {
      bfrag b = *(const bfrag*)(sW + (ct * 16 + lr) * 136 + ks * 32 + lg * 8);
      acc[ct] = MFMA16(a[ks], b, acc[ct]);
    }
  #pragma unroll
  for (int ct = 0; ct < 8; ++ct)
    #pragma unroll
    for (int i = 0; i < 4; ++i)
      ldsb[w][(lg * 4 + i) * 136 + ct * 16 + lr] = f2bf(acc[ct][i]);
  #pragma unroll
  for (int j = 0; j < 4; ++j) {
    int c = j * 64 + l;
    int rw = c >> 4, ch = c & 15;
    int r = r0 + rw;
    if (r < M)
      *(uint4*)(C + (size_t)r * 128 + ch * 8) = *(const uint4*)&ldsb[w][rw * 136 + ch * 8];
  }
}

// ------------------------------------------------------------- GCN aggregate
// wave per node; 16 colgrp x 4 edgegrp, 4 edges per edgegrp in flight (16 total)
__global__ __launch_bounds__(256) void agg_kernel(
    const u16* __restrict__ xw, const float* __restrict__ dis,
    const int* __restrict__ row_ptr, const int* __restrict__ csr_src,
    const float* __restrict__ bias, const float* __restrict__ lng,
    const float* __restrict__ lnb, u16* __restrict__ out, int N, int doLN) {
  int t = threadIdx.x;
  int n = blockIdx.x * 4 + (t >> 6);
  if (n >= N) return;
  int l = t & 63, cg = l & 15, eg = l >> 4;
  float dn = dis[n];
  float acc[8] = {0.f, 0.f, 0.f, 0.f, 0.f, 0.f, 0.f, 0.f};
  if (eg == 0) {
    uint4 r = *(const uint4*)(xw + (size_t)n * 128 + cg * 8);
    float w = dn * dn;
    acc[0] += w * bflo(r.x); acc[1] += w * bfhi(r.x);
    acc[2] += w * bflo(r.y); acc[3] += w * bfhi(r.y);
    acc[4] += w * bflo(r.z); acc[5] += w * bfhi(r.z);
    acc[6] += w * bflo(r.w); acc[7] += w * bfhi(r.w);
  }
  int e1 = row_ptr[n + 1];
  int e = row_ptr[n] + eg;
  int sn0 = (e < e1) ? csr_src[e] : -1;
  int sn1 = (e + 4 < e1) ? csr_src[e + 4] : -1;
  int sn2 = (e + 8 < e1) ? csr_src[e + 8] : -1;
  int sn3 = (e + 12 < e1) ? csr_src[e + 12] : -1;
  while (sn0 >= 0) {
    int s0 = sn0;
    int s1 = (sn1 >= 0) ? sn1 : s0;
    int s2 = (sn2 >= 0) ? sn2 : s0;
    int s3 = (sn3 >= 0) ? sn3 : s0;
    float w0 = dis[s0] * dn;
    float w1 = (sn1 >= 0) ? dis[s1] * dn : 0.f;
    float w2 = (sn2 >= 0) ? dis[s2] * dn : 0.f;
    float w3 = (sn3 >= 0) ? dis[s3] * dn : 0.f;
    e += 16;
    sn0 = (e < e1) ? csr_src[e] : -1;
    sn1 = (e + 4 < e1) ? csr_src[e + 4] : -1;
    sn2 = (e + 8 < e1) ? csr_src[e + 8] : -1;
    sn3 = (e + 12 < e1) ? csr_src[e + 12] : -1;
    uint4 r0 = *(const uint4*)(xw + (size_t)s0 * 128 + cg * 8);
    uint4 r1 = *(const uint4*)(xw + (size_t)s1 * 128 + cg * 8);
    uint4 r2 = *(const uint4*)(xw + (size_t)s2 * 128 + cg * 8);
    uint4 r3 = *(const uint4*)(xw + (size_t)s3 * 128 + cg * 8);
    acc[0] += w0 * bflo(r0.x); acc[1] += w0 * bfhi(r0.x);
    acc[2] += w0 * bflo(r0.y); acc[3] += w0 * bfhi(r0.y);
    acc[4] += w0 * bflo(r0.z); acc[5] += w0 * bfhi(r0.z);
    acc[6] += w0 * bflo(r0.w); acc[7] += w0 * bfhi(r0.w);
    acc[0] += w1 * bflo(r1.x); acc[1] += w1 * bfhi(r1.x);
    acc[2] += w1 * bflo(r1.y); acc[3] += w1 * bfhi(r1.y);
    acc[4] += w1 * bflo(r1.z); acc[5] += w1 * bfhi(r1.z);
    acc[6] += w1 * bflo(r1.w); acc[7] += w1 * bfhi(r1.w);
    acc[0] += w2 * bflo(r2.x); acc[1] += w2 * bfhi(r2.x);
    acc[2] += w2 * bflo(r2.y); acc[3] += w2 * bfhi(r2.y);
    acc[4] += w2 * bflo(r2.z); acc[5] += w2 * bfhi(r2.z);
    acc[6] += w2 * bflo(r2.w); acc[7] += w2 * bfhi(r2.w);
    acc[0] += w3 * bflo(r3.x); acc[1] += w3 * bfhi(r3.x);
    acc[2] += w3 * bflo(r3.y); acc[3] += w3 * bfhi(r3.y);
    acc[4] += w3 * bflo(r3.z); acc[5] += w3 * bfhi(r3.z);
    acc[6] += w3 * bflo(r3.w); acc[7] += w3 * bfhi(r3.w);
  }
  #pragma unroll
  for (int j = 0; j < 8; ++j) {
    acc[j] += __shfl_xor(acc[j], 16);
    acc[j] += __shfl_xor(acc[j], 32);
  }
  int c0 = cg * 8;
  #pragma unroll
  for (int j = 0; j < 8; ++j) acc[j] = fmaxf(acc[j] + bias[c0 + j], 0.f);
  if (doLN) {
    float s1 = 0.f, s2 = 0.f;
    #pragma unroll
    for (int j = 0; j < 8; ++j) { s1 += acc[j]; s2 += acc[j] * acc[j]; }
    #pragma unroll
    for (int off = 1; off < 16; off <<= 1) {
      s1 += __shfl_xor(s1, off);
      s2 += __shfl_xor(s2, off);
    }
    float mean = s1 * (1.f / 128.f);
    float var = s2 * (1.f / 128.f) - mean * mean;
    float inv = rsqrtf(var + 1e-5f);
    #pragma unroll
    for (int j = 0; j < 8; ++j)
      acc[j] = (acc[j] - mean) * inv * lng[c0 + j] + lnb[c0 + j];
  }
  if (eg == 0) {
    uint4 o;
    o.x = pack2(acc[0], acc[1]); o.y = pack2(acc[2], acc[3]);
    o.z = pack2(acc[4], acc[5]); o.w = pack2(acc[6], acc[7]);
    *(uint4*)(out + (size_t)n * 128 + cg * 8) = o;
  }
}

// ----------------------- merged QKV with block-level weight staging in LDS
// role A (inter->kh,vh) / role B (qh, pre-scaled by 0.25*log2(e) for exp2).
__global__ __launch_bounds__(256) void qkv_kernel(
    const u16* __restrict__ xa, const int* __restrict__ hist,
    const int* __restrict__ ans, const int* __restrict__ nseq,
    const u16* __restrict__ l0T, const float* __restrict__ pc,
    const u16* __restrict__ wkT, const float* __restrict__ bk,
    const u16* __restrict__ wvT, const float* __restrict__ bv,
    const u16* __restrict__ wqT, const float* __restrict__ bq,
    u16* __restrict__ khout, u16* __restrict__ vhout,
    u16* __restrict__ qhout, int nblk) {
  __shared__ u16 sW[128 * 136];        // staged weight, padded stride
  __shared__ u16 ldsb[4][16 * 136];    // per-wave bounce
  int bb = blockIdx.x;
  int t = threadIdx.x, w = t >> 6, l = t & 63, lr = l & 15, lg = l >> 4;
  f32x4 acc[8];

  if (bb < nblk) {
    // ---- role A ----
    int r0 = bb * 64 + w * 16;
    int arow = hist[r0 + lr];
    const u16* Arow = xa + (size_t)arow * 128;
    bfrag a[4];
    #pragma unroll
    for (int ks = 0; ks < 4; ++ks) a[ks] = *(const bfrag*)(Arow + ks * 32 + lg * 8);

    STAGE_W(l0T);
    __syncthreads();
    #pragma unroll
    for (int ct = 0; ct < 8; ++ct) acc[ct] = (f32x4){0.f, 0.f, 0.f, 0.f};
    #pragma unroll
    for (int ks = 0; ks < 4; ++ks)
      #pragma unroll
      for (int ct = 0; ct < 8; ++ct) {
        bfrag b = *(const bfrag*)(sW + (ct * 16 + lr) * 136 + ks * 32 + lg * 8);
        acc[ct] = MFMA16(a[ks], b, acc[ct]);
      }
    int pcoff[4];
    #pragma unroll
    for (int i = 0; i < 4; ++i) {
      int r = r0 + lg * 4 + i;
      pcoff[i] = (ans[r] * S_ + (r % S_)) * 128;
    }
    #pragma unroll
    for (int ct = 0; ct < 8; ++ct) {
      int col = ct * 16 + lr;
      #pragma unroll
      for (int i = 0; i < 4; ++i)
        ldsb[w][(lg * 4 + i) * 136 + col] = f2bf(acc[ct][i] + pc[pcoff[i] + col]);
    }
    bfrag a2[4];
    #pragma unroll
    for (int ks = 0; ks < 4; ++ks)
      a2[ks] = *(const bfrag*)(&ldsb[w][lr * 136 + ks * 32 + lg * 8]);
    __syncthreads();           // all waves done reading sW(l0T)

    STAGE_W(wkT);
    __syncthreads();
    #pragma unroll
    for (int ct = 0; ct < 8; ++ct) acc[ct] = (f32x4){0.f, 0.f, 0.f, 0.f};
    #pragma unroll
    for (int ks = 0; ks < 4; ++ks)
      #pragma unroll
      for (int ct = 0; ct < 8; ++ct) {
        bfrag b = *(const bfrag*)(sW + (ct * 16 + lr) * 136 + ks * 32 + lg * 8);
        acc[ct] = MFMA16(a2[ks], b, acc[ct]);
      }
    #pragma unroll
    for (int ct = 0; ct < 8; ++ct)
      #pragma unroll
      for (int i = 0; i < 4; ++i)
        ldsb[w][(lg * 4 + i) * 136 + ct * 16 + lr] = f2bf(acc[ct][i] + bk[ct * 16 + lr]);
    #pragma unroll
    for (int j = 0; j < 4; ++j) {
      int c = j * 64 + l;
      int head = c >> 5, rw = (c >> 1) & 15, half = c & 1;
      *(uint4*)(khout + ((size_t)head * BS_ + r0 + rw) * 16 + half * 8) =
          *(const uint4*)&ldsb[w][rw * 136 + head * 16 + half * 8];
    }
    __syncthreads();           // done reading sW(wkT)

    STAGE_W(wvT);
    __syncthreads();
    #pragma unroll
    for (int ct = 0; ct < 8; ++ct) acc[ct] = (f32x4){0.f, 0.f, 0.f, 0.f};
    #pragma unroll
    for (int ks = 0; ks < 4; ++ks)
      #pragma unroll
      for (int ct = 0; ct < 8; ++ct) {
        bfrag b = *(const bfrag*)(sW + (ct * 16 + lr) * 136 + ks * 32 + lg * 8);
        acc[ct] = MFMA16(a2[ks], b, acc[ct]);
      }
    #pragma unroll
    for (int ct = 0; ct < 8; ++ct)
      #pragma unroll
      for (int i = 0; i < 4; ++i)
        ldsb[w][(lg * 4 + i) * 136 + ct * 16 + lr] = f2bf(acc[ct][i] + bv[ct * 16 + lr]);
    #pragma unroll
    for (int j = 0; j < 4; ++j) {
      int c = j * 64 + l;
      int head = c >> 5, rw = (c >> 1) & 15, half = c & 1;
      *(uint4*)(vhout + ((size_t)head * BS_ + r0 + rw) * 16 + half * 8) =
          *(const uint4*)&ldsb[w][rw * 136 + head * 16 + half * 8];
    }
  } else {
    // ---- role B: qh scaled by 0.25*log2(e) (exp2 form of score scale) ----
    int r0 = (bb - nblk) * 64 + w * 16;
    int arow = nseq[r0 + lr];
    const u16* Arow = xa + (size_t)arow * 128;
    bfrag a[4];
    #pragma unroll
    for (int ks = 0; ks < 4; ++ks) a[ks] = *(const bfrag*)(Arow + ks * 32 + lg * 8);

    STAGE_W(wqT);
    __syncthreads();
    #pragma unroll
    for (int ct = 0; ct < 8; ++ct) acc[ct] = (f32x4){0.f, 0.f, 0.f, 0.f};
    #pragma unroll
    for (int ks = 0; ks < 4; ++ks)
      #pragma unroll
      for (int ct = 0; ct < 8; ++ct) {
        bfrag b = *(const bfrag*)(sW + (ct * 16 + lr) * 136 + ks * 32 + lg * 8);
        acc[ct] = MFMA16(a[ks], b, acc[ct]);
      }
    #pragma unroll
    for (int ct = 0; ct < 8; ++ct)
      #pragma unroll
      for (int i = 0; i < 4; ++i)
        ldsb[w][(lg * 4 + i) * 136 + ct * 16 + lr] =
            f2bf((acc[ct][i] + bq[ct * 16 + lr]) * 0.36067376022224085f);
    #pragma unroll
    for (int j = 0; j < 4; ++j) {
      int c = j * 64 + l;
      int head = c >> 5, rw = (c >> 1) & 15, half = c & 1;
      *(uint4*)(qhout + ((size_t)head * BS_ + r0 + rw) * 16 + half * 8) =
          *(const uint4*)&ldsb[w][rw * 136 + head * 16 + half * 8];
    }
  }
}

// ----------------------------------------------------------- MFMA attention
// Register-P flash attention via swapped operands; exp2 softmax.
__global__ __launch_bounds__(256) void attn_mfma_kernel(
    u16* qh_ao, const u16* __restrict__ kh, const u16* __restrict__ vh) {
  __shared__ u16 Kl[208 * KSTR];   // [key][d0..15]
  __shared__ u16 Vt[16 * VSTR];    // [d][key], keys>=200 zero
  int b = blockIdx.x >> 3, h = blockIdx.x & 7;
  int t = threadIdx.x;
  size_t base = ((size_t)h * BS_ + (size_t)b * S_) * 16;

  for (int i = t; i < 208 * 2; i += 256) {
    int key = i >> 1, d = (i & 1) * 8;
    uint4 v = make_uint4(0, 0, 0, 0);
    if (key < S_) v = *(const uint4*)(kh + base + (size_t)key * 16 + d);
    *(uint4*)(Kl + key * KSTR + d) = v;
  }
  for (int i = t; i < 16 * VSTR; i += 256) {
    int d = i / VSTR, key = i - d * VSTR;
    Vt[d * VSTR + key] = (key < S_) ? vh[base + (size_t)key * 16 + d] : (u16)0;
  }
  __syncthreads();

  int w = t >> 6, l = t & 63, lr = l & 15, lg = l >> 4;
  const f32x4 zero4 = {0.f, 0.f, 0.f, 0.f};
  const bfrag zerob = (bfrag){0, 0, 0, 0, 0, 0, 0, 0};
  u32 qpack = (w == 0) ? 0xFC71u : (w == 1) ? 0xFB80u : (w == 2) ? 0xFA92u : 0x6543u;
  int srcA = lr + ((lg & 1) << 5);
  int srcB = srcA + 16;
  bool hiTile = (lg >= 2);

  for (int s = 0; s < 4; ++s) {
    int qi = (qpack >> (4 * s)) & 15;
    if (qi == 15) break;
    int qrow = qi * 16 + lr;
    bfrag qf = zerob;
    if (lg < 2 && qrow < S_)
      qf = *(const bfrag*)(qh_ao + base + (size_t)qrow * 16 + lg * 8);
    float rsum = 0.f;
    f32x4 o = zero4;
    int ktmax = (qi + 2) >> 1;
    for (int kt = 0; kt < ktmax; ++kt) {
      int kj0 = kt * 2, kj1 = kt * 2 + 1;
      u32 P0t0, P1t0, P0t1 = 0, P1t1 = 0;
      {
        bfrag kf = zerob;
        if (lg < 2) kf = *(const bfrag*)(Kl + (kj0 * 16 + lr) * KSTR + lg * 8);
        f32x4 sc = MFMA16(kf, qf, zero4);
        float p0, p1, p2, p3;
        if (kj0 == qi) {
          p0 = (lg * 4 + 0 <= lr) ? exp2fast(sc[0]) : 0.f;
          p1 = (lg * 4 + 1 <= lr) ? exp2fast(sc[1]) : 0.f;
          p2 = (lg * 4 + 2 <= lr) ? exp2fast(sc[2]) : 0.f;
          p3 = (lg * 4 + 3 <= lr) ? exp2fast(sc[3]) : 0.f;
        } else {
          p0 = exp2fast(sc[0]); p1 = exp2fast(sc[1]);
          p2 = exp2fast(sc[2]); p3 = exp2fast(sc[3]);
        }
        rsum += (p0 + p1) + (p2 + p3);
        P0t0 = pack2(p0, p1); P1t0 = pack2(p2, p3);
      }
      if (kj1 <= qi) {
        bfrag kf = zerob;
        if (lg < 2) kf = *(const bfrag*)(Kl + (kj1 * 16 + lr) * KSTR + lg * 8);
        f32x4 sc = MFMA16(kf, qf, zero4);
        float p0, p1, p2, p3;
        if (kj1 == qi) {
          p0 = (lg * 4 + 0 <= lr) ? exp2fast(sc[0]) : 0.f;
          p1 = (lg * 4 + 1 <= lr) ? exp2fast(sc[1]) : 0.f;
          p2 = (lg * 4 + 2 <= lr) ? exp2fast(sc[2]) : 0.f;
          p3 = (lg * 4 + 3 <= lr) ? exp2fast(sc[3]) : 0.f;
        } else {
          p0 = exp2fast(sc[0]); p1 = exp2fast(sc[1]);
          p2 = exp2fast(sc[2]); p3 = exp2fast(sc[3]);
        }
        rsum += (p0 + p1) + (p2 + p3);
        P0t1 = pack2(p0, p1); P1t1 = pack2(p2, p3);
      }
      u32 x0 = __shfl(P0t0, srcA), x1 = __shfl(P1t0, srcA);
      u32 x2 = __shfl(P0t0, srcB), x3 = __shfl(P1t0, srcB);
      u32 y0 = __shfl(P0t1, srcA), y1 = __shfl(P1t1, srcA);
      u32 y2 = __shfl(P0t1, srcB), y3 = __shfl(P1t1, srcB);
      i32x4 pi;
      pi[0] = (int)(hiTile ? y0 : x0);
      pi[1] = (int)(hiTile ? y1 : x1);
      pi[2] = (int)(hiTile ? y2 : x2);
      pi[3] = (int)(hiTile ? y3 : x3);
      bfrag pb = __builtin_bit_cast(bfrag, pi);
      bfrag vf = *(const bfrag*)(Vt + lr * VSTR + kt * 32 + lg * 8);
      o = MFMA16(vf, pb, o);
    }
    rsum += __shfl_xor(rsum, 16);
    rsum += __shfl_xor(rsum, 32);
    if (qrow < S_) {
      float inv = 1.f / rsum;
      uint2 ov;
      ov.x = pack2(o[0] * inv, o[1] * inv);
      ov.y = pack2(o[2] * inv, o[3] * inv);
      *(uint2*)(qh_ao + base + (size_t)qrow * 16 + lg * 4) = ov;
    }
  }
}

// ---- fused output with staged weights:
// ao@wo + gather(new)@l3T + bo -> LN2 -> FFN -> LN3 -> pred
__global__ __launch_bounds__(256) void out_kernel(
    const u16* __restrict__ ao, const u16* __restrict__ xa,
    const int* __restrict__ nseq,
    const u16* __restrict__ woT, const float* __restrict__ bo,
    const u16* __restrict__ l3T,
    const float* __restrict__ g2, const float* __restrict__ b2,
    const u16* __restrict__ f0T, const float* __restrict__ b0f,
    const u16* __restrict__ f1T, const float* __restrict__ b1f,
    const float* __restrict__ g3, const float* __restrict__ b3,
    const float* __restrict__ w4, const float* __restrict__ b4,
    float* __restrict__ pred) {
  __shared__ u16 sW[128 * 136];
  __shared__ u16 ldsb[4][16 * 136];
  int t = threadIdx.x, w = t >> 6, l = t & 63, lr = l & 15, lg = l >> 4;
  int r0 = blockIdx.x * 64 + w * 16;

  bfrag a_ao[4], a_xa[4];
  #pragma unroll
  for (int ks = 0; ks < 4; ++ks) {
    int head = ks * 2 + (lg >> 1);
    int d0 = (lg & 1) * 8;
    a_ao[ks] = *(const bfrag*)(ao + ((size_t)head * BS_ + r0 + lr) * 16 + d0);
  }
  {
    int arow = nseq[r0 + lr];
    const u16* Arow = xa + (size_t)arow * 128;
    #pragma unroll
    for (int ks = 0; ks < 4; ++ks) a_xa[ks] = *(const bfrag*)(Arow + ks * 32 + lg * 8);
  }

  f32x4 acc[8];
  #pragma unroll
  for (int ct = 0; ct < 8; ++ct) acc[ct] = (f32x4){0.f, 0.f, 0.f, 0.f};

  STAGE_W(woT);
  __syncthreads();
  #pragma unroll
  for (int ks = 0; ks < 4; ++ks)
    #pragma unroll
    for (int ct = 0; ct < 8; ++ct) {
      bfrag b = *(const bfrag*)(sW + (ct * 16 + lr) * 136 + ks * 32 + lg * 8);
      acc[ct] = MFMA16(a_ao[ks], b, acc[ct]);
    }
  __syncthreads();

  STAGE_W(l3T);
  __syncthreads();
  #pragma unroll
  for (int ks = 0; ks < 4; ++ks)
    #pragma unroll
    for (int ct = 0; ct < 8; ++ct) {
      bfrag b = *(const bfrag*)(sW + (ct * 16 + lr) * 136 + ks * 32 + lg * 8);
      acc[ct] = MFMA16(a_xa[ks], b, acc[ct]);
    }
  __syncthreads();

  #pragma unroll
  for (int ct = 0; ct < 8; ++ct) {
    float bcol = bo[ct * 16 + lr];
    #pragma unroll
    for (int i = 0; i < 4; ++i) acc[ct][i] += bcol;
  }
  // LN2 -> acc holds atn (f32); bounce to ldsb; read a2 frags
  bfrag a2[4];
  {
    float s1[4] = {0, 0, 0, 0}, s2[4] = {0, 0, 0, 0};
    #pragma unroll
    for (int ct = 0; ct < 8; ++ct)
      #pragma unroll
      for (int i = 0; i < 4; ++i) {
        s1[i] += acc[ct][i];
        s2[i] += acc[ct][i] * acc[ct][i];
      }
    #pragma unroll
    for (int i = 0; i < 4; ++i) {
      s1[i] += __shfl_xor(s1[i], 1); s2[i] += __shfl_xor(s2[i], 1);
      s1[i] += __shfl_xor(s1[i], 2); s2[i] += __shfl_xor(s2[i], 2);
      s1[i] += __shfl_xor(s1[i], 4); s2[i] += __shfl_xor(s2[i], 4);
      s1[i] += __shfl_xor(s1[i], 8); s2[i] += __shfl_xor(s2[i], 8);
    }
    float mean[4], inv[4];
    #pragma unroll
    for (int i = 0; i < 4; ++i) {
      mean[i] = s1[i] * (1.f / 128.f);
      float var = s2[i] * (1.f / 128.f) - mean[i] * mean[i];
      inv[i] = rsqrtf(var + 1e-5f);
    }
    #pragma unroll
    for (int ct = 0; ct < 8; ++ct) {
      int col = ct * 16 + lr;
      float gc = g2[col], bc = b2[col];
      #pragma unroll
      for (int i = 0; i < 4; ++i) {
        acc[ct][i] = (acc[ct][i] - mean[i]) * inv[i] * gc + bc;
        ldsb[w][(lg * 4 + i) * 136 + col] = f2bf(acc[ct][i]);
      }
    }
    #pragma unroll
    for (int ks = 0; ks < 4; ++ks)
      a2[ks] = *(const bfrag*)(&ldsb[w][lr * 136 + ks * 32 + lg * 8]);
  }

  STAGE_W(f0T);
  __syncthreads();
  f32x4 acc2[8];
  #pragma unroll
  for (int ct = 0; ct < 8; ++ct) acc2[ct] = (f32x4){0.f, 0.f, 0.f, 0.f};
  #pragma unroll
  for (int ks = 0; ks < 4; ++ks)
    #pragma unroll
    for (int ct = 0; ct < 8; ++ct) {
      bfrag b = *(const bfrag*)(sW + (ct * 16 + lr) * 136 + ks * 32 + lg * 8);
      acc2[ct] = MFMA16(a2[ks], b, acc2[ct]);
    }
  #pragma unroll
  for (int ct = 0; ct < 8; ++ct) {
    int col = ct * 16 + lr;
    float bcol = b0f[col];
    #pragma unroll
    for (int i = 0; i < 4; ++i)
      ldsb[w][(lg * 4 + i) * 136 + col] = f2bf(fmaxf(acc2[ct][i] + bcol, 0.f));
  }
  #pragma unroll
  for (int ks = 0; ks < 4; ++ks)
    a2[ks] = *(const bfrag*)(&ldsb[w][lr * 136 + ks * 32 + lg * 8]);
  __syncthreads();

  STAGE_W(f1T);
  __syncthreads();
  #pragma unroll
  for (int ct = 0; ct < 8; ++ct) acc2[ct] = (f32x4){0.f, 0.f, 0.f, 0.f};
  #pragma unroll
  for (int ks = 0; ks < 4; ++ks)
    #pragma unroll
    for (int ct = 0; ct < 8; ++ct) {
      bfrag b = *(const bfrag*)(sW + (ct * 16 + lr) * 136 + ks * 32 + lg * 8);
      acc2[ct] = MFMA16(a2[ks], b, acc2[ct]);
    }
  #pragma unroll
  for (int ct = 0; ct < 8; ++ct) {
    int col = ct * 16 + lr;
    float bcol = b1f[col];
    #pragma unroll
    for (int i = 0; i < 4; ++i) acc2[ct][i] += bcol + acc[ct][i];
  }
  // LN3 -> dot w4 -> pred
  {
    float s1[4] = {0, 0, 0, 0}, s2[4] = {0, 0, 0, 0};
    #pragma unroll
    for (int ct = 0; ct < 8; ++ct)
      #pragma unroll
      for (int i = 0; i < 4; ++i) {
        s1[i] += acc2[ct][i];
        s2[i] += acc2[ct][i] * acc2[ct][i];
      }
    #pragma unroll
    for (int i = 0; i < 4; ++i) {
      s1[i] += __shfl_xor(s1[i], 1); s2[i] += __shfl_xor(s2[i], 1);
      s1[i] += __shfl_xor(s1[i], 2); s2[i] += __shfl_xor(s2[i], 2);
      s1[i] += __shfl_xor(s1[i], 4); s2[i] += __shfl_xor(s2[i], 4);
      s1[i] += __shfl_xor(s1[i], 8); s2[i] += __shfl_xor(s2[i], 8);
    }
    float p[4] = {0, 0, 0, 0};
    #pragma unroll
    for (int i = 0; i < 4; ++i) {
      float mean = s1[i] * (1.f / 128.f);
      float var = s2[i] * (1.f / 128.f) - mean * mean;
      float inv = rsqrtf(var + 1e-5f);
      #pragma unroll
      for (int ct = 0; ct < 8; ++ct) {
        int col = ct * 16 + lr;
        p[i] += ((acc2[ct][i] - mean) * inv * g3[col] + b3[col]) * w4[col];
      }
    }
    #pragma unroll
    for (int i = 0; i < 4; ++i) {
      p[i] += __shfl_xor(p[i], 1);
      p[i] += __shfl_xor(p[i], 2);
      p[i] += __shfl_xor(p[i], 4);
      p[i] += __shfl_xor(p[i], 8);
    }
    if (lr == 0) {
      float bias4 = b4[0];
      #pragma unroll
      for (int i = 0; i < 4; ++i) pred[r0 + lg * 4 + i] = p[i] + bias4;
    }
  }
}

// ---------------------------------------------------------------------------
extern "C" void kernel_launch(void* const* d_in, const int* in_sizes, int n_in,
                              void* d_out, int out_size, void* d_ws, size_t ws_size,
                              hipStream_t stream) {
  const int* hist_seq = (const int*)d_in[0];
  const int* hist_ans = (const int*)d_in[1];
  const int* new_seq = (const int*)d_in[2];
  const int* edge_index = (const int*)d_in[3];
  const float* node_x = (const float*)d_in[4];
  const float* gcn_w0 = (const float*)d_in[5];
  const float* gcn_b0 = (const float*)d_in[6];
  const float* gcn_w1 = (const float*)d_in[7];
  const float* gcn_b1 = (const float*)d_in[8];
  const float* gcn_w2 = (const float*)d_in[9];
  const float* gcn_b2 = (const float*)d_in[10];
  const float* ln0_g = (const float*)d_in[11];
  const float* ln0_b = (const float*)d_in[12];
  const float* ln1_g = (const float*)d_in[13];
  const float* ln1_b = (const float*)d_in[14];
  const float* ln2_g = (const float*)d_in[15];
  const float* ln2_b = (const float*)d_in[16];
  const float* ln3_g = (const float*)d_in[17];
  const float* ln3_b = (const float*)d_in[18];
  const float* corr_emb = (const float*)d_in[19];
  const float* lin0_w = (const float*)d_in[20];
  const float* lin0_b = (const float*)d_in[21];
  const float* lin1_w = (const float*)d_in[22];
  const float* lin2_w = (const float*)d_in[23];
  const float* lin3_w = (const float*)d_in[24];
  const float* lin4_w = (const float*)d_in[25];
  const float* lin4_b = (const float*)d_in[26];
  const float* pos_emb = (const float*)d_in[27];
  const float* mha_wq = (const float*)d_in[28];
  const float* mha_bq = (const float*)d_in[29];
  const float* mha_wk = (const float*)d_in[30];
  const float* mha_bk = (const float*)d_in[31];
  const float* mha_wv = (const float*)d_in[32];
  const float* mha_bv = (const float*)d_in[33];
  const float* mha_wo = (const float*)d_in[34];
  const float* mha_bo = (const float*)d_in[35];
  const float* ffn0_w = (const float*)d_in[36];
  const float* ffn0_b = (const float*)d_in[37];
  const float* ffn1_w = (const float*)d_in[38];
  const float* ffn1_b = (const float*)d_in[39];
  (void)in_sizes; (void)n_in; (void)out_size;

  char* ws = (char*)d_ws;
  size_t off = 0;
  auto alloc = [&](size_t bytes) -> void* {
    void* p = ws + off;
    off += (bytes + 255) & ~(size_t)255;
    return p;
  };
  int* cnt = (int*)alloc((size_t)N_NODES * 4);
  int* row_ptr = (int*)alloc((size_t)(N_NODES + 1) * 4);
  int* fill = (int*)alloc((size_t)N_NODES * 4);
  int* locpref = (int*)alloc((size_t)N_NODES * 4);
  int* btot = (int*)alloc(64 * 4);
  int* boff = (int*)alloc(64 * 4);
  float* dis = (float*)alloc((size_t)N_NODES * 4);
  int* csr_src = (int*)alloc((size_t)N_EDGES * 4);
  const size_t WB = 128 * 128 * 2;
  u16* g0T = (u16*)alloc(WB);
  u16* g1T = (u16*)alloc(WB);
  u16* g2T = (u16*)alloc(WB);
  u16* l0T = (u16*)alloc(WB);
  u16* l3T = (u16*)alloc(WB);
  u16* woT = (u16*)alloc(WB);
  u16* f0T = (u16*)alloc(WB);
  u16* f1T = (u16*)alloc(WB);
  u16* wqT = (u16*)alloc(WB);
  u16* wkT = (u16*)alloc(WB);
  u16* wvT = (u16*)alloc(WB);
  float* pc = (float*)alloc((size_t)2 * S_ * 128 * 4);
  u16* xa = (u16*)alloc((size_t)N_NODES * 128 * 2);
  const size_t CB = (size_t)BS_ * 128 * 2;   // 26.2 MB
  size_t RB = off;
  u16* bufQ = (u16*)(ws + RB);                // qh -> ao in place, head-major
  u16* bufK = (u16*)(ws + RB + CB);           // kh head-major
  u16* bufV = (u16*)(ws + RB + 2 * CB);       // vh head-major
  u16* xb = bufQ;                             // overlay: dead before qkv writes
  u16* xw = bufQ + (size_t)N_NODES * 128;
  size_t need = RB + 3 * CB;
  if (ws_size < need) return;     // diagnostic guard

  // ---- fused prep (zero cnt, weight transposes/products, pc, node_x cast) ----
  prep_kernel<<<4225, 256, 0, stream>>>(cnt, gcn_w0, gcn_w1, gcn_w2, lin0_w, lin3_w,
                                        mha_wo, ffn0_w, ffn1_w, lin1_w, lin2_w,
                                        mha_wq, mha_wk, mha_wv, corr_emb, lin0_b,
                                        pos_emb, node_x, g0T, g1T, g2T, l0T, l3T,
                                        woT, f0T, f1T, wqT, wkT, wvT, pc, xb);
  // ---- graph prep ----
  int nb = (N_NODES + 1023) / 1024;   // 49
  hist_kernel<<<(N_EDGES + 255) / 256, 256, 0, stream>>>(edge_index + N_EDGES, cnt, N_EDGES);
  scanA_kernel<<<nb, 1024, 0, stream>>>(cnt, locpref, btot, dis, N_NODES);
  scanB_kernel<<<1, 64, 0, stream>>>(btot, boff, nb);
  scanC_kernel<<<(N_NODES + 255) / 256, 256, 0, stream>>>(locpref, boff, row_ptr, fill, N_NODES);
  scatter_kernel<<<(N_EDGES + 255) / 256, 256, 0, stream>>>(edge_index, edge_index + N_EDGES,
                                                            fill, csr_src, N_EDGES);

  int gN = (N_NODES + 63) / 64;
  int aN = (N_NODES + 3) / 4;

  // ---- GCN ----
  gemm_bf16_kernel<<<gN, 256, 0, stream>>>(xb, g0T, xw, N_NODES);
  agg_kernel<<<aN, 256, 0, stream>>>(xw, dis, row_ptr, csr_src, gcn_b0, ln0_g, ln0_b, xa, N_NODES, 1);
  gemm_bf16_kernel<<<gN, 256, 0, stream>>>(xa, g1T, xw, N_NODES);
  agg_kernel<<<aN, 256, 0, stream>>>(xw, dis, row_ptr, csr_src, gcn_b1, ln1_g, ln1_b, xa, N_NODES, 1);
  gemm_bf16_kernel<<<gN, 256, 0, stream>>>(xa, g2T, xw, N_NODES);
  agg_kernel<<<aN, 256, 0, stream>>>(xw, dis, row_ptr, csr_src, gcn_b2, nullptr, nullptr, xa, N_NODES, 0);

  // ---- transformer, full batch, 3 dispatches ----
  int gT = BS_ / 64;   // 1600
  qkv_kernel<<<2 * gT, 256, 0, stream>>>(xa, hist_seq, hist_ans, new_seq,
                                         l0T, pc, wkT, mha_bk, wvT, mha_bv,
                                         wqT, mha_bq, bufK, bufV, bufQ, gT);
  attn_mfma_kernel<<<B_ * 8, 256, 0, stream>>>(bufQ, bufK, bufV);
  out_kernel<<<gT, 256, 0, stream>>>(bufQ, xa, new_seq, woT, mha_bo, l3T,
                                     ln2_g, ln2_b, f0T, ffn0_b, f1T, ffn1_b,
                                     ln3_g, ln3_b, lin4_w, lin4_b, (float*)d_out);
}